// Round 13
// baseline (8084.654 us; speedup 1.0000x reference)
//
#include <hip/hip_runtime.h>
#include <hip/hip_bf16.h>
#include <hip/hip_cooperative_groups.h>

namespace cg = cooperative_groups;

// B=1024, F=1024, S=64, 64 steps.
//   basep  = bf16x4 gate-packed (q @ Wq_perm^T + biases)   (once)
//   Wcomb  = [W_hh | (support@Wr^T)^T]_perm rows  (once, bf16, K=1088)
// R13: persistent cooperative kernel (R8-verified 2-buffer 48KB loop, reg-
// resident basep/query/c, 3-blk/CU headroom so 512-block coop launch fits)
// with HOST FALLBACK to the verified R11 per-step path if the cooperative
// launch is rejected (return code checked).

typedef __attribute__((ext_vector_type(8))) __bf16 bf16x8;
typedef __attribute__((ext_vector_type(4))) float f32x4;

#define MFMA __builtin_amdgcn_mfma_f32_16x16x32_bf16

__device__ __forceinline__ ushort f2bf(float f) {
  union { float f; unsigned int u; } v; v.f = f;
  unsigned int u = v.u;
  u += 0x7FFFu + ((u >> 16) & 1u);   // RNE
  return (ushort)(u >> 16);
}
__device__ __forceinline__ float bf2f(ushort u) {
  union { float f; unsigned int u; } v; v.u = ((unsigned int)u) << 16; return v.f;
}
__device__ __forceinline__ float sigm_(float x) { return 1.f / (1.f + __expf(-x)); }
__device__ __forceinline__ float tanh_(float x) {
  x = fminf(15.f, fmaxf(-15.f, x));
  float e = __expf(2.f * x);
  return (e - 1.f) / (e + 1.f);
}
__device__ __forceinline__ void async16(ushort* lds, const ushort* g) {
  __builtin_amdgcn_global_load_lds(
      (const __attribute__((address_space(1))) void*)g,
      (__attribute__((address_space(3))) void*)lds, 16, 0, 0);
}
__device__ __forceinline__ int permrow(int n) {   // n = gate*1024 + j
  int g = n >> 10, j = n & 1023;
  return ((j >> 4) << 6) | (g << 4) | (j & 15);
}

// ---------------- precompute ------------------------------------------------
__global__ __launch_bounds__(256) void prep_kernel(
    const float* __restrict__ query, const float* __restrict__ support,
    const float* __restrict__ W_ih, const float* __restrict__ W_hh,
    const float* __restrict__ b_ih, const float* __restrict__ b_hh,
    ushort* __restrict__ Wq_bf, ushort* __restrict__ Wcomb,
    float* __restrict__ bias_p, ushort* __restrict__ X0,
    float* __restrict__ c, ushort* __restrict__ Wr_bf,
    ushort* __restrict__ Sb)
{
  int g = blockIdx.x * 256 + threadIdx.x;        // 0 .. 4M-1
  int n = g >> 10, k = g & 1023;
  int np = permrow(n);
  Wq_bf[(size_t)np * 1024 + k] = f2bf(W_ih[(size_t)n * 2048 + k]);
  Wr_bf[(size_t)n * 1024 + k]  = f2bf(W_ih[(size_t)n * 2048 + 1024 + k]);
  Wcomb[(size_t)np * 1088 + k] = f2bf(W_hh[(size_t)n * 1024 + k]);
  if (g < 1024 * 1024) {
    X0[g] = f2bf(query[g]);
    c[g] = 0.f;
  }
  if (g < 4096) bias_p[permrow(g)] = b_ih[g] + b_hh[g];
  if (g < 65536) Sb[g] = f2bf(support[g]);     // bf16 row-major support [64][1024]
}

// ---- SW^T via MFMA: C[n][s] = sum_k Wr_bf[n][k]*Sb[s][k] -> Wcomb perm cols
__global__ __launch_bounds__(256) void sw_mfma(
    const ushort* __restrict__ Wr, const ushort* __restrict__ Sb,
    ushort* __restrict__ Wcomb)
{
  __shared__ ushort As[3][128 * 32];   // 24 KB
  __shared__ ushort Bs[3][64 * 32];    // 12 KB
  const int t = threadIdx.x;
  const int bm0 = blockIdx.x * 128;
  const int w = t >> 6, l = t & 63;
  const int wm = w * 32;
  const int srow = t >> 2, scol = (t & 3) * 8;
  const ushort* ga0 = Wr + (size_t)(bm0 + srow) * 1024 + scol;
  const ushort* ga1 = Wr + (size_t)(bm0 + 64 + srow) * 1024 + scol;
  const ushort* gb0 = Sb + (size_t)srow * 1024 + scol;
  const int fr = l & 15, fk = (l >> 4) * 8, fq = l >> 4;
  f32x4 acc[2][4] = {};
  const int nt = 32;   // K=1024
  async16(&As[0][t * 8], ga0); async16(&As[0][2048 + t * 8], ga1);
  async16(&Bs[0][t * 8], gb0);
  async16(&As[1][t * 8], ga0 + 32); async16(&As[1][2048 + t * 8], ga1 + 32);
  async16(&Bs[1][t * 8], gb0 + 32);
  for (int it = 0; it < nt; it++) {
    if (it + 1 < nt) { asm volatile("s_waitcnt vmcnt(3)" ::: "memory"); }
    else             { asm volatile("s_waitcnt vmcnt(0)" ::: "memory"); }
    __builtin_amdgcn_s_barrier();
    __builtin_amdgcn_sched_barrier(0);
    const int b = it % 3;
    const ushort* pa = &As[b][(wm + fr) * 32 + fk];
    const ushort* pb = &Bs[b][fr * 32 + fk];
    bf16x8 af[2], bfv[4];
#pragma unroll
    for (int mi = 0; mi < 2; mi++) af[mi] = *(const bf16x8*)(pa + mi * 512);
#pragma unroll
    for (int ni = 0; ni < 4; ni++) bfv[ni] = *(const bf16x8*)(pb + ni * 512);
    if (it + 2 < nt) {
      const int pbuf = (it + 2) % 3;
      const int k0 = (it + 2) << 5;
      async16(&As[pbuf][t * 8], ga0 + k0); async16(&As[pbuf][2048 + t * 8], ga1 + k0);
      async16(&Bs[pbuf][t * 8], gb0 + k0);
    }
#pragma unroll
    for (int mi = 0; mi < 2; mi++)
#pragma unroll
      for (int ni = 0; ni < 4; ni++)
        acc[mi][ni] = MFMA(af[mi], bfv[ni], acc[mi][ni], 0, 0, 0);
  }
#pragma unroll
  for (int mi = 0; mi < 2; mi++)
#pragma unroll
    for (int ni = 0; ni < 4; ni++) {
      int s = ni * 16 + fr;
      int row0 = bm0 + wm + mi * 16 + fq * 4;
#pragma unroll
      for (int jj = 0; jj < 4; jj++)
        Wcomb[(size_t)permrow(row0 + jj) * 1088 + 1024 + s] = f2bf(acc[mi][ni][jj]);
    }
}

// ------- base GEMM (once): basep = bf16x4 gate-pack(X0 @ Wq^T + bias) ------
__global__ __launch_bounds__(256) void gemm_base(
    const ushort* __restrict__ A, const ushort* __restrict__ Bw,
    const float* __restrict__ bias, ushort* __restrict__ basep)
{
  __shared__ ushort As[3][2][64 * 32];
  __shared__ ushort Bs[3][2][128 * 32];
  const int t = threadIdx.x;
  const int bid = blockIdx.x;
  const int xcd = bid & 7, idx = bid >> 3;
  const int bx = idx & 15, byy = idx >> 4;
  const int by = xcd * 4 + byy;
  const int m0 = bx * 64, n0 = by * 128;
  const int w = t >> 6, l = t & 63;
  const int wm = (w >> 1) * 32, wn = (w & 1) * 64;
  const int srow = t >> 2, scol = (t & 3) * 8;
  const ushort* ga  = A  + (size_t)(m0 + srow) * 1024 + scol;
  const ushort* gb0 = Bw + (size_t)(n0 + srow) * 1024 + scol;
  const ushort* gb1 = Bw + (size_t)(n0 + 64 + srow) * 1024 + scol;
  const int fr = l & 15, fk = (l >> 4) * 8, fq = l >> 4;
  f32x4 acc[2][4] = {};
  const int nt = 16;
#define BSTAGE(buf, k0)                                       \
  async16(&As[buf][0][t * 8], ga + (k0));                     \
  async16(&As[buf][1][t * 8], ga + (k0) + 32);                \
  async16(&Bs[buf][0][t * 8], gb0 + (k0));                    \
  async16(&Bs[buf][0][2048 + t * 8], gb1 + (k0));             \
  async16(&Bs[buf][1][t * 8], gb0 + (k0) + 32);               \
  async16(&Bs[buf][1][2048 + t * 8], gb1 + (k0) + 32);
  BSTAGE(0, 0)
  BSTAGE(1, 64)
  for (int it = 0; it < nt; it++) {
    if (it + 1 < nt) { asm volatile("s_waitcnt vmcnt(6)" ::: "memory"); }
    else             { asm volatile("s_waitcnt vmcnt(0)" ::: "memory"); }
    __builtin_amdgcn_s_barrier();
    __builtin_amdgcn_sched_barrier(0);
    if (it + 2 < nt) { const int pb = (it + 2) % 3; const int k0 = (it + 2) << 6; BSTAGE(pb, k0) }
    const int b = it % 3;
#pragma unroll
    for (int kk = 0; kk < 2; kk++) {
      const ushort* pa = &As[b][kk][(wm + fr) * 32 + fk];
      const ushort* pb2 = &Bs[b][kk][(wn + fr) * 32 + fk];
      bf16x8 af[2], bfv[4];
#pragma unroll
      for (int mi = 0; mi < 2; mi++) af[mi] = *(const bf16x8*)(pa + mi * 512);
#pragma unroll
      for (int ni = 0; ni < 4; ni++) bfv[ni] = *(const bf16x8*)(pb2 + ni * 512);
      __builtin_amdgcn_s_setprio(1);
#pragma unroll
      for (int mi = 0; mi < 2; mi++)
#pragma unroll
        for (int ni = 0; ni < 4; ni++)
          acc[mi][ni] = MFMA(af[mi], bfv[ni], acc[mi][ni], 0, 0, 0);
      __builtin_amdgcn_s_setprio(0);
    }
  }
#undef BSTAGE
  const int jcol = (((n0 + wn) >> 6) << 4) + fr;
#pragma unroll
  for (int mi = 0; mi < 2; mi++)
#pragma unroll
    for (int jj = 0; jj < 4; jj++) {
      int row = m0 + wm + mi * 16 + fq * 4 + jj;
      ushort4 pk;
      pk.x = f2bf(acc[mi][0][jj] + bias[n0 + wn + fr]);
      pk.y = f2bf(acc[mi][1][jj] + bias[n0 + wn + 16 + fr]);
      pk.z = f2bf(acc[mi][2][jj] + bias[n0 + wn + 32 + fr]);
      pk.w = f2bf(acc[mi][3][jj] + bias[n0 + wn + 48 + fr]);
      *(ushort4*)&basep[((size_t)row * 1024 + jcol) * 4] = pk;
    }
}

// ---------------- R11 per-step kernel (verified FALLBACK path) --------------
__global__ __launch_bounds__(256, 2) void gemm_fused(
    const ushort* __restrict__ A, const ushort* __restrict__ Wcomb,
    const ushort* __restrict__ Sb, const ushort* __restrict__ basep,
    float* __restrict__ cbuf, const float* __restrict__ query,
    ushort* __restrict__ Xout, float* __restrict__ outp)
{
  __shared__ ushort As[3][2][64 * 32];    // 24 KB
  __shared__ ushort Bs[3][2][128 * 32];   // 48 KB
  const int t = threadIdx.x;
  const int bid = blockIdx.x;
  const int xcd = bid & 7, idx = bid >> 3;
  const int bx = idx & 15, byy = idx >> 4;
  const int by = xcd * 4 + byy;
  const int m0 = bx * 64, n0 = by * 128;
  const int w = t >> 6, l = t & 63;
  const int wm = (w >> 1) * 32, wn = (w & 1) * 64;
  const int srow = t >> 2, scol = (t & 3) * 8;
  const ushort* ga  = A + (size_t)(m0 + srow) * 1024 + scol;
  const ushort* gb0 = Wcomb + (size_t)(n0 + srow) * 1088 + scol;
  const ushort* gb1 = Wcomb + (size_t)(n0 + 64 + srow) * 1088 + scol;
  const int fr = l & 15, fk = (l >> 4) * 8, fq = l >> 4;
  const ushort* gsb = Sb + (size_t)((w & 1) * 32 + fr) * 1024 + fk;
  f32x4 acc[2][4] = {};
  f32x4 lacc[2][2] = {};
#define FSTAGE_A(buf, k0)                                     \
  async16(&As[buf][0][t * 8], ga + (k0));                     \
  async16(&As[buf][1][t * 8], ga + (k0) + 32);
#define FSTAGE_B(buf, k0)                                     \
  async16(&Bs[buf][0][t * 8], gb0 + (k0));                    \
  async16(&Bs[buf][0][2048 + t * 8], gb1 + (k0));             \
  async16(&Bs[buf][1][t * 8], gb0 + (k0) + 32);               \
  async16(&Bs[buf][1][2048 + t * 8], gb1 + (k0) + 32);
  FSTAGE_A(0, 0) FSTAGE_B(0, 0)
  FSTAGE_A(1, 64) FSTAGE_B(1, 64)
  asm volatile("s_waitcnt vmcnt(6)" ::: "memory");
  for (int it = 0; it < 16; it++) {
    __builtin_amdgcn_s_barrier();
    __builtin_amdgcn_sched_barrier(0);
    const int k0 = it << 6;
    bf16x8 sb00 = *(const bf16x8*)(gsb + k0);
    bf16x8 sb01 = *(const bf16x8*)(gsb + k0 + 32);
    bf16x8 sb10 = *(const bf16x8*)(gsb + k0 + 16384);
    bf16x8 sb11 = *(const bf16x8*)(gsb + k0 + 16384 + 32);
    if (it <= 13) { const int pb = (it + 2) % 3; FSTAGE_A(pb, k0 + 128) FSTAGE_B(pb, k0 + 128) }
    else if (it == 14) { FSTAGE_B(1, 1024) }
    const int b = it % 3;
    bf16x8 af2[2][2];
#pragma unroll
    for (int kk = 0; kk < 2; kk++) {
      const ushort* pa = &As[b][kk][(wm + fr) * 32 + fk];
      const ushort* pb2 = &Bs[b][kk][(wn + fr) * 32 + fk];
      bf16x8 bfv[4];
#pragma unroll
      for (int mi = 0; mi < 2; mi++) af2[kk][mi] = *(const bf16x8*)(pa + mi * 512);
#pragma unroll
      for (int ni = 0; ni < 4; ni++) bfv[ni] = *(const bf16x8*)(pb2 + ni * 512);
      __builtin_amdgcn_s_setprio(1);
#pragma unroll
      for (int mi = 0; mi < 2; mi++)
#pragma unroll
        for (int ni = 0; ni < 4; ni++)
          acc[mi][ni] = MFMA(af2[kk][mi], bfv[ni], acc[mi][ni], 0, 0, 0);
      __builtin_amdgcn_s_setprio(0);
    }
    if (it <= 13)      { asm volatile("s_waitcnt vmcnt(6)" ::: "memory"); }
    else if (it == 14) { asm volatile("s_waitcnt vmcnt(4)" ::: "memory"); }
    else               { asm volatile("s_waitcnt vmcnt(0)" ::: "memory"); }
    __builtin_amdgcn_sched_barrier(0);
    lacc[0][0] = MFMA(af2[0][0], sb00, lacc[0][0], 0, 0, 0);
    lacc[0][1] = MFMA(af2[0][0], sb10, lacc[0][1], 0, 0, 0);
    lacc[1][0] = MFMA(af2[0][1], sb00, lacc[1][0], 0, 0, 0);
    lacc[1][1] = MFMA(af2[0][1], sb10, lacc[1][1], 0, 0, 0);
    lacc[0][0] = MFMA(af2[1][0], sb01, lacc[0][0], 0, 0, 0);
    lacc[0][1] = MFMA(af2[1][0], sb11, lacc[0][1], 0, 0, 0);
    lacc[1][0] = MFMA(af2[1][1], sb01, lacc[1][0], 0, 0, 0);
    lacc[1][1] = MFMA(af2[1][1], sb11, lacc[1][1], 0, 0, 0);
  }
#undef FSTAGE_A
#undef FSTAGE_B
  const int jcol = (((n0 + wn) >> 6) << 4) + fr;
  ushort4 bpk[2][4];
  float qv[2][4], cv[2][4];
#pragma unroll
  for (int mi = 0; mi < 2; mi++)
#pragma unroll
    for (int jj = 0; jj < 4; jj++) {
      int row = m0 + wm + mi * 16 + fq * 4 + jj;
      size_t cidx = (size_t)row * 1024 + jcol;
      bpk[mi][jj] = *(const ushort4*)&basep[cidx * 4];
      qv[mi][jj] = query[cidx];
      cv[mi][jj] = cbuf[cidx];
    }
  asm volatile("s_waitcnt lgkmcnt(0)" ::: "memory");
  __builtin_amdgcn_s_barrier();
  __builtin_amdgcn_sched_barrier(0);
  {
    float* lg = (float*)&Bs[2][0][0];
    const int sbase = (w & 1) * 32;
#pragma unroll
    for (int mi = 0; mi < 2; mi++)
#pragma unroll
      for (int ni = 0; ni < 2; ni++) {
        int s = sbase + ni * 16 + fr;
        int r0 = wm + mi * 16 + fq * 4;
#pragma unroll
        for (int jj = 0; jj < 4; jj++)
          lg[(r0 + jj) * 64 + s] = lacc[mi][ni][jj];
      }
  }
  asm volatile("s_waitcnt lgkmcnt(0)" ::: "memory");
  __builtin_amdgcn_s_barrier();
  __builtin_amdgcn_sched_barrier(0);
  {
    const int r = t >> 2, q = t & 3;
    float* lg = (float*)&Bs[2][0][0];
    float p[16];
#pragma unroll
    for (int i = 0; i < 16; i++) p[i] = lg[r * 64 + q * 16 + i];
    float mx = p[0];
#pragma unroll
    for (int i = 1; i < 16; i++) mx = fmaxf(mx, p[i]);
    mx = fmaxf(mx, __shfl_xor(mx, 1));
    mx = fmaxf(mx, __shfl_xor(mx, 2));
    float sm = 0.f;
#pragma unroll
    for (int i = 0; i < 16; i++) { p[i] = __expf(p[i] - mx); sm += p[i]; }
    sm += __shfl_xor(sm, 1);
    sm += __shfl_xor(sm, 2);
    float inv = 1.f / sm;
    ushort* at = &As[2][q >> 1][r * 32 + (q & 1) * 16];
#pragma unroll
    for (int i = 0; i < 16; i++) at[i] = f2bf(p[i] * inv);
  }
  asm volatile("s_waitcnt lgkmcnt(0)" ::: "memory");
  __builtin_amdgcn_s_barrier();
  __builtin_amdgcn_sched_barrier(0);
#pragma unroll
  for (int kk = 0; kk < 2; kk++) {
    const ushort* pa = &As[2][kk][(wm + fr) * 32 + fk];
    const ushort* pb2 = &Bs[1][kk][(wn + fr) * 32 + fk];
    bf16x8 af[2], bfv[4];
#pragma unroll
    for (int mi = 0; mi < 2; mi++) af[mi] = *(const bf16x8*)(pa + mi * 512);
#pragma unroll
    for (int ni = 0; ni < 4; ni++) bfv[ni] = *(const bf16x8*)(pb2 + ni * 512);
    __builtin_amdgcn_s_setprio(1);
#pragma unroll
    for (int mi = 0; mi < 2; mi++)
#pragma unroll
      for (int ni = 0; ni < 4; ni++)
        acc[mi][ni] = MFMA(af[mi], bfv[ni], acc[mi][ni], 0, 0, 0);
    __builtin_amdgcn_s_setprio(0);
  }
#pragma unroll
  for (int mi = 0; mi < 2; mi++) {
#pragma unroll
    for (int jj = 0; jj < 4; jj++) {
      int row = m0 + wm + mi * 16 + fq * 4 + jj;
      size_t cidx = (size_t)row * 1024 + jcol;
      ushort4 pk = bpk[mi][jj];
      float gi = acc[mi][0][jj] + bf2f(pk.x);
      float gf = acc[mi][1][jj] + bf2f(pk.y);
      float gg = acc[mi][2][jj] + bf2f(pk.z);
      float go = acc[mi][3][jj] + bf2f(pk.w);
      float cn = sigm_(gf) * cv[mi][jj] + sigm_(gi) * tanh_(gg);
      float hn = sigm_(go) * tanh_(cn) + qv[mi][jj];
      cbuf[cidx] = cn;
      Xout[cidx] = f2bf(hn);
      if (outp) outp[cidx] = hn;
    }
  }
}

// -------- persistent kernel: all 64 steps, R8 2-buf loop, state in regs -----
__global__ __launch_bounds__(256, 2) void gemm_fused_all(
    ushort* __restrict__ X0, ushort* __restrict__ X1,
    const ushort* __restrict__ Wcomb, const ushort* __restrict__ Sb,
    const ushort* __restrict__ basep, const float* __restrict__ query,
    float* __restrict__ outp)
{
  cg::grid_group grid = cg::this_grid();
  __shared__ ushort As[2][2][64 * 32];    // 16 KB
  __shared__ ushort Bs[2][2][128 * 32];   // 32 KB -> 48 KB, 3 blk/CU headroom
  const int t = threadIdx.x;
  const int bid = blockIdx.x;
  const int xcd = bid & 7, idx = bid >> 3;
  const int bx = idx & 15, byy = idx >> 4;
  const int by = xcd * 4 + byy;
  const int m0 = bx * 64, n0 = by * 128;
  const int w = t >> 6, l = t & 63;
  const int wm = (w >> 1) * 32, wn = (w & 1) * 64;
  const int srow = t >> 2, scol = (t & 3) * 8;
  const ushort* gb0 = Wcomb + (size_t)(n0 + srow) * 1088 + scol;
  const ushort* gb1 = Wcomb + (size_t)(n0 + 64 + srow) * 1088 + scol;
  const int fr = l & 15, fk = (l >> 4) * 8, fq = l >> 4;
  const ushort* gsb = Sb + (size_t)((w & 1) * 32 + fr) * 1024 + fk;
  const int jcol = (((n0 + wn) >> 6) << 4) + fr;
  // persistent register state
  ushort4 bpk[2][4];
  float qv[2][4], cv[2][4];
#pragma unroll
  for (int mi = 0; mi < 2; mi++)
#pragma unroll
    for (int jj = 0; jj < 4; jj++) {
      int row = m0 + wm + mi * 16 + fq * 4 + jj;
      size_t cidx = (size_t)row * 1024 + jcol;
      bpk[mi][jj] = *(const ushort4*)&basep[cidx * 4];
      qv[mi][jj] = query[cidx];
      cv[mi][jj] = 0.f;
    }
#define PSTAGE_A(buf, k0)                                     \
  async16(&As[buf][0][t * 8], ga + (k0));                     \
  async16(&As[buf][1][t * 8], ga + (k0) + 32);
#define PSTAGE_B(buf, k0)                                     \
  async16(&Bs[buf][0][t * 8], gb0 + (k0));                    \
  async16(&Bs[buf][0][2048 + t * 8], gb1 + (k0));             \
  async16(&Bs[buf][1][t * 8], gb0 + (k0) + 32);               \
  async16(&Bs[buf][1][2048 + t * 8], gb1 + (k0) + 32);
  for (int step = 0; step < 64; ++step) {
    const ushort* Xc = (step & 1) ? X1 : X0;
    ushort*       Xn = (step & 1) ? X0 : X1;
    const ushort* ga = Xc + (size_t)(m0 + srow) * 1024 + scol;
    f32x4 acc[2][4] = {};
    f32x4 lacc[2][2] = {};
    PSTAGE_A(0, 0) PSTAGE_B(0, 0)
    asm volatile("s_waitcnt vmcnt(0)" ::: "memory");
    for (int it = 0; it < 16; it++) {
      __builtin_amdgcn_s_barrier();
      const int cur = it & 1, nxt = cur ^ 1;
      const int k0 = it << 6;
      const int ka = (it < 15) ? (k0 + 64) : 960;    // it==15: dummy-A restage
      const int kb = (it < 15) ? (k0 + 64) : 1024;   // it==15: B tail (K=1024)
      PSTAGE_A(nxt, ka) PSTAGE_B(nxt, kb)            // 6 VMEM
      bf16x8 sb00 = *(const bf16x8*)(gsb + k0);
      bf16x8 sb01 = *(const bf16x8*)(gsb + k0 + 32);
      bf16x8 sb10 = *(const bf16x8*)(gsb + k0 + 16384);
      bf16x8 sb11 = *(const bf16x8*)(gsb + k0 + 16384 + 32);
      bf16x8 af2[2][2];
#pragma unroll
      for (int kk = 0; kk < 2; kk++) {
        const ushort* pa = &As[cur][kk][(wm + fr) * 32 + fk];
        const ushort* pb2 = &Bs[cur][kk][(wn + fr) * 32 + fk];
        bf16x8 bfv[4];
#pragma unroll
        for (int mi = 0; mi < 2; mi++) af2[kk][mi] = *(const bf16x8*)(pa + mi * 512);
#pragma unroll
        for (int ni = 0; ni < 4; ni++) bfv[ni] = *(const bf16x8*)(pb2 + ni * 512);
        __builtin_amdgcn_s_setprio(1);
#pragma unroll
        for (int mi = 0; mi < 2; mi++)
#pragma unroll
          for (int ni = 0; ni < 4; ni++)
            acc[mi][ni] = MFMA(af2[kk][mi], bfv[ni], acc[mi][ni], 0, 0, 0);
        __builtin_amdgcn_s_setprio(0);
      }
      asm volatile("s_waitcnt vmcnt(6)" ::: "memory");
      __builtin_amdgcn_sched_barrier(0);
      lacc[0][0] = MFMA(af2[0][0], sb00, lacc[0][0], 0, 0, 0);
      lacc[0][1] = MFMA(af2[0][0], sb10, lacc[0][1], 0, 0, 0);
      lacc[1][0] = MFMA(af2[0][1], sb00, lacc[1][0], 0, 0, 0);
      lacc[1][1] = MFMA(af2[0][1], sb10, lacc[1][1], 0, 0, 0);
      lacc[0][0] = MFMA(af2[1][0], sb01, lacc[0][0], 0, 0, 0);
      lacc[0][1] = MFMA(af2[1][0], sb11, lacc[0][1], 0, 0, 0);
      lacc[1][0] = MFMA(af2[1][1], sb01, lacc[1][0], 0, 0, 0);
      lacc[1][1] = MFMA(af2[1][1], sb11, lacc[1][1], 0, 0, 0);
      asm volatile("s_waitcnt vmcnt(0)" ::: "memory");   // own stage drained
    }
    // softmax interlude (lg = Bs[1] consumed tile15; attn -> As[0])
    __builtin_amdgcn_s_barrier();
    {
      float* lg = (float*)&Bs[1][0][0];
      const int sbase = (w & 1) * 32;
#pragma unroll
      for (int mi = 0; mi < 2; mi++)
#pragma unroll
        for (int ni = 0; ni < 2; ni++) {
          int s = sbase + ni * 16 + fr;
          int r0 = wm + mi * 16 + fq * 4;
#pragma unroll
          for (int jj = 0; jj < 4; jj++)
            lg[(r0 + jj) * 64 + s] = lacc[mi][ni][jj];
        }
    }
    __syncthreads();
    {
      const int r = t >> 2, q = t & 3;
      float* lg = (float*)&Bs[1][0][0];
      float p[16];
#pragma unroll
      for (int i = 0; i < 16; i++) p[i] = lg[r * 64 + q * 16 + i];
      float mx = p[0];
#pragma unroll
      for (int i = 1; i < 16; i++) mx = fmaxf(mx, p[i]);
      mx = fmaxf(mx, __shfl_xor(mx, 1));
      mx = fmaxf(mx, __shfl_xor(mx, 2));
      float sm = 0.f;
#pragma unroll
      for (int i = 0; i < 16; i++) { p[i] = __expf(p[i] - mx); sm += p[i]; }
      sm += __shfl_xor(sm, 1);
      sm += __shfl_xor(sm, 2);
      float inv = 1.f / sm;
      ushort* at = &As[0][q >> 1][r * 32 + (q & 1) * 16];
#pragma unroll
      for (int i = 0; i < 16; i++) at[i] = f2bf(p[i] * inv);
    }
    __syncthreads();
    // phase 16: attn (As[0]) x SW^T (Bs[0] tail)
#pragma unroll
    for (int kk = 0; kk < 2; kk++) {
      const ushort* pa = &As[0][kk][(wm + fr) * 32 + fk];
      const ushort* pb2 = &Bs[0][kk][(wn + fr) * 32 + fk];
      bf16x8 af[2], bfv[4];
#pragma unroll
      for (int mi = 0; mi < 2; mi++) af[mi] = *(const bf16x8*)(pa + mi * 512);
#pragma unroll
      for (int ni = 0; ni < 4; ni++) bfv[ni] = *(const bf16x8*)(pb2 + ni * 512);
      __builtin_amdgcn_s_setprio(1);
#pragma unroll
      for (int mi = 0; mi < 2; mi++)
#pragma unroll
        for (int ni = 0; ni < 4; ni++)
          acc[mi][ni] = MFMA(af[mi], bfv[ni], acc[mi][ni], 0, 0, 0);
      __builtin_amdgcn_s_setprio(0);
    }
    // epilogue: LSTM on register state
#pragma unroll
    for (int mi = 0; mi < 2; mi++) {
#pragma unroll
      for (int jj = 0; jj < 4; jj++) {
        int row = m0 + wm + mi * 16 + fq * 4 + jj;
        size_t cidx = (size_t)row * 1024 + jcol;
        ushort4 pk = bpk[mi][jj];
        float gi = acc[mi][0][jj] + bf2f(pk.x);
        float gf = acc[mi][1][jj] + bf2f(pk.y);
        float gg = acc[mi][2][jj] + bf2f(pk.z);
        float go = acc[mi][3][jj] + bf2f(pk.w);
        float cn = sigm_(gf) * cv[mi][jj] + sigm_(gi) * tanh_(gg);
        float hn = sigm_(go) * tanh_(cn) + qv[mi][jj];
        cv[mi][jj] = cn;
        Xn[cidx] = f2bf(hn);
        if (step == 63) outp[cidx] = hn;
      }
    }
    __threadfence();
    grid.sync();
  }
#undef PSTAGE_A
#undef PSTAGE_B
}

extern "C" void kernel_launch(void* const* d_in, const int* in_sizes, int n_in,
                              void* d_out, int out_size, void* d_ws, size_t ws_size,
                              hipStream_t stream) {
  const float* query   = (const float*)d_in[0];
  const float* support = (const float*)d_in[1];
  const float* W_ih    = (const float*)d_in[2];
  const float* W_hh    = (const float*)d_in[3];
  const float* b_ih    = (const float*)d_in[4];
  const float* b_hh    = (const float*)d_in[5];
  float* out = (float*)d_out;

  char* ws = (char*)d_ws;
  size_t off = 0;
  auto alloc = [&](size_t bytes) {
    void* p = ws + off;
    off += (bytes + 255) & ~(size_t)255;
    return p;
  };
  ushort* Wq_bf  = (ushort*)alloc((size_t)4096 * 1024 * 2);
  ushort* Wcomb  = (ushort*)alloc((size_t)4096 * 1088 * 2);
  ushort* Wr_bf  = (ushort*)alloc((size_t)4096 * 1024 * 2);
  ushort* Sb     = (ushort*)alloc((size_t)64 * 1024 * 2);
  float*  bias_p = (float*) alloc((size_t)4096 * 4);
  ushort* basep  = (ushort*)alloc((size_t)1024 * 4096 * 2);
  ushort* X0     = (ushort*)alloc((size_t)1024 * 1024 * 2);
  ushort* X1     = (ushort*)alloc((size_t)1024 * 1024 * 2);
  float*  c      = (float*) alloc((size_t)1024 * 1024 * 4);

  prep_kernel<<<16384, 256, 0, stream>>>(query, support, W_ih, W_hh, b_ih, b_hh,
                                         Wq_bf, Wcomb, bias_p, X0, c, Wr_bf, Sb);
  sw_mfma<<<32, 256, 0, stream>>>(Wr_bf, Sb, Wcomb);
  gemm_base<<<512, 256, 0, stream>>>(X0, Wq_bf, bias_p, basep);

  void* args[] = { &X0, &X1, &Wcomb, &Sb, &basep, (void*)&query, &out };
  hipError_t err = hipLaunchCooperativeKernel((const void*)gemm_fused_all,
                                              dim3(512), dim3(256), args, 0, stream);
  if (err != hipSuccess) {
    // verified R11 per-step fallback
    for (int step = 0; step < 64; step++) {
      ushort* Xc = (step & 1) ? X1 : X0;
      ushort* Xn = (step & 1) ? X0 : X1;
      gemm_fused<<<512, 256, 0, stream>>>(Xc, Wcomb, Sb, basep,
                                          c, query, Xn,
                                          (step == 63) ? out : nullptr);
    }
  }
}

// Round 14
// 1836.471 us; speedup vs baseline: 4.4023x; 4.4023x over previous
//
#include <hip/hip_runtime.h>
#include <hip/hip_bf16.h>

// B=1024, F=1024, S=64, 64 steps.
//   basep  = bf16x4 gate-packed (q @ Wq_perm^T + biases)   (once)
//   Wcomb  = [W_hh | (support@Wr^T)^T]_perm rows  (once, bf16, K=1088)
//   step (ONE kernel): 17-phase gemm gates = [h|attn] @ Wcomb^T + basep.
// R14 = R11 (verified best, 1837us) + bf16 query (qb) in the LSTM epilogue
// (-2 MB/step of compulsory stream). Persistent/cooperative path abandoned:
// R13 measured grid.sync() at ~100us/step (8345us total).

typedef __attribute__((ext_vector_type(8))) __bf16 bf16x8;
typedef __attribute__((ext_vector_type(4))) float f32x4;

#define MFMA __builtin_amdgcn_mfma_f32_16x16x32_bf16

__device__ __forceinline__ ushort f2bf(float f) {
  union { float f; unsigned int u; } v; v.f = f;
  unsigned int u = v.u;
  u += 0x7FFFu + ((u >> 16) & 1u);   // RNE
  return (ushort)(u >> 16);
}
__device__ __forceinline__ float bf2f(ushort u) {
  union { float f; unsigned int u; } v; v.u = ((unsigned int)u) << 16; return v.f;
}
__device__ __forceinline__ float sigm_(float x) { return 1.f / (1.f + __expf(-x)); }
__device__ __forceinline__ float tanh_(float x) {
  x = fminf(15.f, fmaxf(-15.f, x));
  float e = __expf(2.f * x);
  return (e - 1.f) / (e + 1.f);
}
__device__ __forceinline__ void async16(ushort* lds, const ushort* g) {
  __builtin_amdgcn_global_load_lds(
      (const __attribute__((address_space(1))) void*)g,
      (__attribute__((address_space(3))) void*)lds, 16, 0, 0);
}
__device__ __forceinline__ int permrow(int n) {   // n = gate*1024 + j
  int g = n >> 10, j = n & 1023;
  return ((j >> 4) << 6) | (g << 4) | (j & 15);
}

// ---------------- precompute ------------------------------------------------
__global__ __launch_bounds__(256) void prep_kernel(
    const float* __restrict__ query, const float* __restrict__ support,
    const float* __restrict__ W_ih, const float* __restrict__ W_hh,
    const float* __restrict__ b_ih, const float* __restrict__ b_hh,
    ushort* __restrict__ Wq_bf, ushort* __restrict__ Wcomb,
    float* __restrict__ bias_p, ushort* __restrict__ X0,
    float* __restrict__ c, ushort* __restrict__ Wr_bf,
    ushort* __restrict__ Sb, ushort* __restrict__ qb)
{
  int g = blockIdx.x * 256 + threadIdx.x;        // 0 .. 4M-1
  int n = g >> 10, k = g & 1023;
  int np = permrow(n);
  Wq_bf[(size_t)np * 1024 + k] = f2bf(W_ih[(size_t)n * 2048 + k]);
  Wr_bf[(size_t)n * 1024 + k]  = f2bf(W_ih[(size_t)n * 2048 + 1024 + k]);
  Wcomb[(size_t)np * 1088 + k] = f2bf(W_hh[(size_t)n * 1024 + k]);
  if (g < 1024 * 1024) {
    ushort qv = f2bf(query[g]);
    X0[g] = qv;
    qb[g] = qv;
    c[g] = 0.f;
  }
  if (g < 4096) bias_p[permrow(g)] = b_ih[g] + b_hh[g];
  if (g < 65536) Sb[g] = f2bf(support[g]);     // bf16 row-major support [64][1024]
}

// ---- SW^T via MFMA: C[n][s] = sum_k Wr_bf[n][k]*Sb[s][k] -> Wcomb perm cols
__global__ __launch_bounds__(256) void sw_mfma(
    const ushort* __restrict__ Wr, const ushort* __restrict__ Sb,
    ushort* __restrict__ Wcomb)
{
  __shared__ ushort As[3][128 * 32];   // 24 KB
  __shared__ ushort Bs[3][64 * 32];    // 12 KB
  const int t = threadIdx.x;
  const int bm0 = blockIdx.x * 128;
  const int w = t >> 6, l = t & 63;
  const int wm = w * 32;
  const int srow = t >> 2, scol = (t & 3) * 8;
  const ushort* ga0 = Wr + (size_t)(bm0 + srow) * 1024 + scol;
  const ushort* ga1 = Wr + (size_t)(bm0 + 64 + srow) * 1024 + scol;
  const ushort* gb0 = Sb + (size_t)srow * 1024 + scol;
  const int fr = l & 15, fk = (l >> 4) * 8, fq = l >> 4;
  f32x4 acc[2][4] = {};
  const int nt = 32;   // K=1024
  async16(&As[0][t * 8], ga0); async16(&As[0][2048 + t * 8], ga1);
  async16(&Bs[0][t * 8], gb0);
  async16(&As[1][t * 8], ga0 + 32); async16(&As[1][2048 + t * 8], ga1 + 32);
  async16(&Bs[1][t * 8], gb0 + 32);
  for (int it = 0; it < nt; it++) {
    if (it + 1 < nt) { asm volatile("s_waitcnt vmcnt(3)" ::: "memory"); }
    else             { asm volatile("s_waitcnt vmcnt(0)" ::: "memory"); }
    __builtin_amdgcn_s_barrier();
    __builtin_amdgcn_sched_barrier(0);
    const int b = it % 3;
    const ushort* pa = &As[b][(wm + fr) * 32 + fk];
    const ushort* pb = &Bs[b][fr * 32 + fk];
    bf16x8 af[2], bfv[4];
#pragma unroll
    for (int mi = 0; mi < 2; mi++) af[mi] = *(const bf16x8*)(pa + mi * 512);
#pragma unroll
    for (int ni = 0; ni < 4; ni++) bfv[ni] = *(const bf16x8*)(pb + ni * 512);
    if (it + 2 < nt) {
      const int pbuf = (it + 2) % 3;
      const int k0 = (it + 2) << 5;
      async16(&As[pbuf][t * 8], ga0 + k0); async16(&As[pbuf][2048 + t * 8], ga1 + k0);
      async16(&Bs[pbuf][t * 8], gb0 + k0);
    }
#pragma unroll
    for (int mi = 0; mi < 2; mi++)
#pragma unroll
      for (int ni = 0; ni < 4; ni++)
        acc[mi][ni] = MFMA(af[mi], bfv[ni], acc[mi][ni], 0, 0, 0);
  }
#pragma unroll
  for (int mi = 0; mi < 2; mi++)
#pragma unroll
    for (int ni = 0; ni < 4; ni++) {
      int s = ni * 16 + fr;
      int row0 = bm0 + wm + mi * 16 + fq * 4;
#pragma unroll
      for (int jj = 0; jj < 4; jj++)
        Wcomb[(size_t)permrow(row0 + jj) * 1088 + 1024 + s] = f2bf(acc[mi][ni][jj]);
    }
}

// ------- base GEMM (once): basep = bf16x4 gate-pack(X0 @ Wq^T + bias) ------
__global__ __launch_bounds__(256) void gemm_base(
    const ushort* __restrict__ A, const ushort* __restrict__ Bw,
    const float* __restrict__ bias, ushort* __restrict__ basep)
{
  __shared__ ushort As[3][2][64 * 32];
  __shared__ ushort Bs[3][2][128 * 32];
  const int t = threadIdx.x;
  const int bid = blockIdx.x;
  const int xcd = bid & 7, idx = bid >> 3;
  const int bx = idx & 15, byy = idx >> 4;
  const int by = xcd * 4 + byy;
  const int m0 = bx * 64, n0 = by * 128;
  const int w = t >> 6, l = t & 63;
  const int wm = (w >> 1) * 32, wn = (w & 1) * 64;
  const int srow = t >> 2, scol = (t & 3) * 8;
  const ushort* ga  = A  + (size_t)(m0 + srow) * 1024 + scol;
  const ushort* gb0 = Bw + (size_t)(n0 + srow) * 1024 + scol;
  const ushort* gb1 = Bw + (size_t)(n0 + 64 + srow) * 1024 + scol;
  const int fr = l & 15, fk = (l >> 4) * 8, fq = l >> 4;
  f32x4 acc[2][4] = {};
  const int nt = 16;
#define BSTAGE(buf, k0)                                       \
  async16(&As[buf][0][t * 8], ga + (k0));                     \
  async16(&As[buf][1][t * 8], ga + (k0) + 32);                \
  async16(&Bs[buf][0][t * 8], gb0 + (k0));                    \
  async16(&Bs[buf][0][2048 + t * 8], gb1 + (k0));             \
  async16(&Bs[buf][1][t * 8], gb0 + (k0) + 32);               \
  async16(&Bs[buf][1][2048 + t * 8], gb1 + (k0) + 32);
  BSTAGE(0, 0)
  BSTAGE(1, 64)
  for (int it = 0; it < nt; it++) {
    if (it + 1 < nt) { asm volatile("s_waitcnt vmcnt(6)" ::: "memory"); }
    else             { asm volatile("s_waitcnt vmcnt(0)" ::: "memory"); }
    __builtin_amdgcn_s_barrier();
    __builtin_amdgcn_sched_barrier(0);
    if (it + 2 < nt) { const int pb = (it + 2) % 3; const int k0 = (it + 2) << 6; BSTAGE(pb, k0) }
    const int b = it % 3;
#pragma unroll
    for (int kk = 0; kk < 2; kk++) {
      const ushort* pa = &As[b][kk][(wm + fr) * 32 + fk];
      const ushort* pb2 = &Bs[b][kk][(wn + fr) * 32 + fk];
      bf16x8 af[2], bfv[4];
#pragma unroll
      for (int mi = 0; mi < 2; mi++) af[mi] = *(const bf16x8*)(pa + mi * 512);
#pragma unroll
      for (int ni = 0; ni < 4; ni++) bfv[ni] = *(const bf16x8*)(pb2 + ni * 512);
      __builtin_amdgcn_s_setprio(1);
#pragma unroll
      for (int mi = 0; mi < 2; mi++)
#pragma unroll
        for (int ni = 0; ni < 4; ni++)
          acc[mi][ni] = MFMA(af[mi], bfv[ni], acc[mi][ni], 0, 0, 0);
      __builtin_amdgcn_s_setprio(0);
    }
  }
#undef BSTAGE
  const int jcol = (((n0 + wn) >> 6) << 4) + fr;
#pragma unroll
  for (int mi = 0; mi < 2; mi++)
#pragma unroll
    for (int jj = 0; jj < 4; jj++) {
      int row = m0 + wm + mi * 16 + fq * 4 + jj;
      ushort4 pk;
      pk.x = f2bf(acc[mi][0][jj] + bias[n0 + wn + fr]);
      pk.y = f2bf(acc[mi][1][jj] + bias[n0 + wn + 16 + fr]);
      pk.z = f2bf(acc[mi][2][jj] + bias[n0 + wn + 32 + fr]);
      pk.w = f2bf(acc[mi][3][jj] + bias[n0 + wn + 48 + fr]);
      *(ushort4*)&basep[((size_t)row * 1024 + jcol) * 4] = pk;
    }
}

// ------------- fused per-step kernel: gemm + in-flight attention + LSTM -----
__global__ __launch_bounds__(256, 2) void gemm_fused(
    const ushort* __restrict__ A, const ushort* __restrict__ Wcomb,
    const ushort* __restrict__ Sb, const ushort* __restrict__ basep,
    float* __restrict__ cbuf, const ushort* __restrict__ qb,
    ushort* __restrict__ Xout, float* __restrict__ outp)
{
  __shared__ ushort As[3][2][64 * 32];    // 24 KB
  __shared__ ushort Bs[3][2][128 * 32];   // 48 KB
  const int t = threadIdx.x;
  const int bid = blockIdx.x;
  const int xcd = bid & 7, idx = bid >> 3;
  const int bx = idx & 15, byy = idx >> 4;
  const int by = xcd * 4 + byy;
  const int m0 = bx * 64, n0 = by * 128;
  const int w = t >> 6, l = t & 63;
  const int wm = (w >> 1) * 32, wn = (w & 1) * 64;
  const int srow = t >> 2, scol = (t & 3) * 8;
  const ushort* ga  = A + (size_t)(m0 + srow) * 1024 + scol;
  const ushort* gb0 = Wcomb + (size_t)(n0 + srow) * 1088 + scol;
  const ushort* gb1 = Wcomb + (size_t)(n0 + 64 + srow) * 1088 + scol;
  const int fr = l & 15, fk = (l >> 4) * 8, fq = l >> 4;
  const ushort* gsb = Sb + (size_t)((w & 1) * 32 + fr) * 1024 + fk;
  f32x4 acc[2][4] = {};
  f32x4 lacc[2][2] = {};
#define FSTAGE_A(buf, k0)                                     \
  async16(&As[buf][0][t * 8], ga + (k0));                     \
  async16(&As[buf][1][t * 8], ga + (k0) + 32);
#define FSTAGE_B(buf, k0)                                     \
  async16(&Bs[buf][0][t * 8], gb0 + (k0));                    \
  async16(&Bs[buf][0][2048 + t * 8], gb1 + (k0));             \
  async16(&Bs[buf][1][t * 8], gb0 + (k0) + 32);               \
  async16(&Bs[buf][1][2048 + t * 8], gb1 + (k0) + 32);
  FSTAGE_A(0, 0) FSTAGE_B(0, 0)
  FSTAGE_A(1, 64) FSTAGE_B(1, 64)
  asm volatile("s_waitcnt vmcnt(6)" ::: "memory");
  for (int it = 0; it < 16; it++) {
    __builtin_amdgcn_s_barrier();
    __builtin_amdgcn_sched_barrier(0);
    const int k0 = it << 6;
    bf16x8 sb00 = *(const bf16x8*)(gsb + k0);
    bf16x8 sb01 = *(const bf16x8*)(gsb + k0 + 32);
    bf16x8 sb10 = *(const bf16x8*)(gsb + k0 + 16384);
    bf16x8 sb11 = *(const bf16x8*)(gsb + k0 + 16384 + 32);
    if (it <= 13) { const int pb = (it + 2) % 3; FSTAGE_A(pb, k0 + 128) FSTAGE_B(pb, k0 + 128) }
    else if (it == 14) { FSTAGE_B(1, 1024) }
    const int b = it % 3;
    bf16x8 af2[2][2];
#pragma unroll
    for (int kk = 0; kk < 2; kk++) {
      const ushort* pa = &As[b][kk][(wm + fr) * 32 + fk];
      const ushort* pb2 = &Bs[b][kk][(wn + fr) * 32 + fk];
      bf16x8 bfv[4];
#pragma unroll
      for (int mi = 0; mi < 2; mi++) af2[kk][mi] = *(const bf16x8*)(pa + mi * 512);
#pragma unroll
      for (int ni = 0; ni < 4; ni++) bfv[ni] = *(const bf16x8*)(pb2 + ni * 512);
      __builtin_amdgcn_s_setprio(1);
#pragma unroll
      for (int mi = 0; mi < 2; mi++)
#pragma unroll
        for (int ni = 0; ni < 4; ni++)
          acc[mi][ni] = MFMA(af2[kk][mi], bfv[ni], acc[mi][ni], 0, 0, 0);
      __builtin_amdgcn_s_setprio(0);
    }
    if (it <= 13)      { asm volatile("s_waitcnt vmcnt(6)" ::: "memory"); }
    else if (it == 14) { asm volatile("s_waitcnt vmcnt(4)" ::: "memory"); }
    else               { asm volatile("s_waitcnt vmcnt(0)" ::: "memory"); }
    __builtin_amdgcn_sched_barrier(0);
    lacc[0][0] = MFMA(af2[0][0], sb00, lacc[0][0], 0, 0, 0);
    lacc[0][1] = MFMA(af2[0][0], sb10, lacc[0][1], 0, 0, 0);
    lacc[1][0] = MFMA(af2[0][1], sb00, lacc[1][0], 0, 0, 0);
    lacc[1][1] = MFMA(af2[0][1], sb10, lacc[1][1], 0, 0, 0);
    lacc[0][0] = MFMA(af2[1][0], sb01, lacc[0][0], 0, 0, 0);
    lacc[0][1] = MFMA(af2[1][0], sb11, lacc[0][1], 0, 0, 0);
    lacc[1][0] = MFMA(af2[1][1], sb01, lacc[1][0], 0, 0, 0);
    lacc[1][1] = MFMA(af2[1][1], sb11, lacc[1][1], 0, 0, 0);
  }
#undef FSTAGE_A
#undef FSTAGE_B
  // ---- T14 prefetch of epilogue operands (in flight through softmax) ----
  const int jcol = (((n0 + wn) >> 6) << 4) + fr;
  ushort4 bpk[2][4];
  ushort qv16[2][4];
  float cv[2][4];
#pragma unroll
  for (int mi = 0; mi < 2; mi++)
#pragma unroll
    for (int jj = 0; jj < 4; jj++) {
      int row = m0 + wm + mi * 16 + fq * 4 + jj;
      size_t cidx = (size_t)row * 1024 + jcol;
      bpk[mi][jj] = *(const ushort4*)&basep[cidx * 4];
      qv16[mi][jj] = qb[cidx];
      cv[mi][jj] = cbuf[cidx];
    }
  // ---- softmax interlude: RAW barriers (lgkmcnt only; vmem stays in flight)
  asm volatile("s_waitcnt lgkmcnt(0)" ::: "memory");
  __builtin_amdgcn_s_barrier();
  __builtin_amdgcn_sched_barrier(0);
  {
    float* lg = (float*)&Bs[2][0][0];   // scratch: tile14 buffer, consumed
    const int sbase = (w & 1) * 32;
#pragma unroll
    for (int mi = 0; mi < 2; mi++)
#pragma unroll
      for (int ni = 0; ni < 2; ni++) {
        int s = sbase + ni * 16 + fr;
        int r0 = wm + mi * 16 + fq * 4;
#pragma unroll
        for (int jj = 0; jj < 4; jj++)
          lg[(r0 + jj) * 64 + s] = lacc[mi][ni][jj];
      }
  }
  asm volatile("s_waitcnt lgkmcnt(0)" ::: "memory");
  __builtin_amdgcn_s_barrier();
  __builtin_amdgcn_sched_barrier(0);
  {
    const int r = t >> 2, q = t & 3;
    float* lg = (float*)&Bs[2][0][0];
    float p[16];
#pragma unroll
    for (int i = 0; i < 16; i++) p[i] = lg[r * 64 + q * 16 + i];
    float mx = p[0];
#pragma unroll
    for (int i = 1; i < 16; i++) mx = fmaxf(mx, p[i]);
    mx = fmaxf(mx, __shfl_xor(mx, 1));
    mx = fmaxf(mx, __shfl_xor(mx, 2));
    float sm = 0.f;
#pragma unroll
    for (int i = 0; i < 16; i++) { p[i] = __expf(p[i] - mx); sm += p[i]; }
    sm += __shfl_xor(sm, 1);
    sm += __shfl_xor(sm, 2);
    float inv = 1.f / sm;
    ushort* at = &As[2][q >> 1][r * 32 + (q & 1) * 16];
#pragma unroll
    for (int i = 0; i < 16; i++) at[i] = f2bf(p[i] * inv);
  }
  asm volatile("s_waitcnt lgkmcnt(0)" ::: "memory");
  __builtin_amdgcn_s_barrier();
  __builtin_amdgcn_sched_barrier(0);
  // ---- phase 16: attn (As[2]) x SW^T (Bs[1] B-tail) ----
#pragma unroll
  for (int kk = 0; kk < 2; kk++) {
    const ushort* pa = &As[2][kk][(wm + fr) * 32 + fk];
    const ushort* pb2 = &Bs[1][kk][(wn + fr) * 32 + fk];
    bf16x8 af[2], bfv[4];
#pragma unroll
    for (int mi = 0; mi < 2; mi++) af[mi] = *(const bf16x8*)(pa + mi * 512);
#pragma unroll
    for (int ni = 0; ni < 4; ni++) bfv[ni] = *(const bf16x8*)(pb2 + ni * 512);
    __builtin_amdgcn_s_setprio(1);
#pragma unroll
    for (int mi = 0; mi < 2; mi++)
#pragma unroll
      for (int ni = 0; ni < 4; ni++)
        acc[mi][ni] = MFMA(af[mi], bfv[ni], acc[mi][ni], 0, 0, 0);
    __builtin_amdgcn_s_setprio(0);
  }
  // ---- epilogue: lane-local LSTM from prefetched operands ----
#pragma unroll
  for (int mi = 0; mi < 2; mi++) {
#pragma unroll
    for (int jj = 0; jj < 4; jj++) {
      int row = m0 + wm + mi * 16 + fq * 4 + jj;
      size_t cidx = (size_t)row * 1024 + jcol;
      ushort4 pk = bpk[mi][jj];
      float gi = acc[mi][0][jj] + bf2f(pk.x);
      float gf = acc[mi][1][jj] + bf2f(pk.y);
      float gg = acc[mi][2][jj] + bf2f(pk.z);
      float go = acc[mi][3][jj] + bf2f(pk.w);
      float cn = sigm_(gf) * cv[mi][jj] + sigm_(gi) * tanh_(gg);
      float hn = sigm_(go) * tanh_(cn) + bf2f(qv16[mi][jj]);
      cbuf[cidx] = cn;
      Xout[cidx] = f2bf(hn);
      if (outp) outp[cidx] = hn;
    }
  }
}

extern "C" void kernel_launch(void* const* d_in, const int* in_sizes, int n_in,
                              void* d_out, int out_size, void* d_ws, size_t ws_size,
                              hipStream_t stream) {
  const float* query   = (const float*)d_in[0];
  const float* support = (const float*)d_in[1];
  const float* W_ih    = (const float*)d_in[2];
  const float* W_hh    = (const float*)d_in[3];
  const float* b_ih    = (const float*)d_in[4];
  const float* b_hh    = (const float*)d_in[5];
  float* out = (float*)d_out;

  char* ws = (char*)d_ws;
  size_t off = 0;
  auto alloc = [&](size_t bytes) {
    void* p = ws + off;
    off += (bytes + 255) & ~(size_t)255;
    return p;
  };
  ushort* Wq_bf  = (ushort*)alloc((size_t)4096 * 1024 * 2);
  ushort* Wcomb  = (ushort*)alloc((size_t)4096 * 1088 * 2);
  ushort* Wr_bf  = (ushort*)alloc((size_t)4096 * 1024 * 2);
  ushort* Sb     = (ushort*)alloc((size_t)64 * 1024 * 2);
  float*  bias_p = (float*) alloc((size_t)4096 * 4);
  ushort* basep  = (ushort*)alloc((size_t)1024 * 4096 * 2);
  ushort* X0     = (ushort*)alloc((size_t)1024 * 1024 * 2);
  ushort* X1     = (ushort*)alloc((size_t)1024 * 1024 * 2);
  ushort* qb     = (ushort*)alloc((size_t)1024 * 1024 * 2);
  float*  c      = (float*) alloc((size_t)1024 * 1024 * 4);

  prep_kernel<<<16384, 256, 0, stream>>>(query, support, W_ih, W_hh, b_ih, b_hh,
                                         Wq_bf, Wcomb, bias_p, X0, c, Wr_bf,
                                         Sb, qb);
  sw_mfma<<<32, 256, 0, stream>>>(Wr_bf, Sb, Wcomb);
  gemm_base<<<512, 256, 0, stream>>>(X0, Wq_bf, bias_p, basep);
  for (int step = 0; step < 64; step++) {
    ushort* Xc = (step & 1) ? X1 : X0;
    ushort* Xn = (step & 1) ? X0 : X1;
    gemm_fused<<<512, 256, 0, stream>>>(Xc, Wcomb, Sb, basep,
                                        c, qb, Xn,
                                        (step == 63) ? out : nullptr);
  }
}